// Round 9
// baseline (312.011 us; speedup 1.0000x reference)
//
#include <hip/hip_runtime.h>
#include <hip/hip_bf16.h>

// ChebyshevKANLayer: y[b,o] = sum_{i,j} T_j(xhat[b,i]) * C[i,o,j]
// T0==1 folded into fp32 bias; GEMM K = 1024*8 = 8192 (degrees 1..8), bf16 MFMA.
// R15: m201 8-phase template + split-K x2. All coarse-phase structures convoy
// (reads then MFMAs serialize: R9 2419cyc/tile ~= 1506+1242*0.75). The verified
// fix is the fine interleave: per phase {ds_read subtile | stage 1 half-tile}
// barrier; lgkm(0); setprio+16 MFMA; barrier — counted vmcnt(4) ONCE per K-tile.
// Tile 256x256 (8 waves 2Mx4N, wave 128x64, 0.0229 B/F -> compute-bound),
// BK=64 split as 2 k-halves of 32; 8 half-slots x 16KB = 128 KB LDS.
// N=1024 -> grid = 4col x 32row x 2khalf = 256 blocks (full GPU); combine via
// fp32 atomicAdd to pre-zeroed out (2 addends -> commutative -> deterministic).
// Keep: R13 4-chunk XOR pair (0 conflicts), XCD chunk swizzle, R9 frag mapping.
// ws: bias 4KB(pad 64K) | B^T 16.8MB | A 134MB.

typedef __attribute__((ext_vector_type(8))) short bf16x8s;   // MFMA A/B frag (4 VGPRs)
typedef __attribute__((ext_vector_type(4))) float f32x4;     // MFMA C/D frag

constexpr int BROWS = 8192;
constexpr int IDIM  = 1024;
constexpr int ODIM  = 1024;
constexpr int DEG1  = 9;
constexpr int KP    = 8;             // stored degrees 1..8 per input i
constexpr int KD    = IDIM * KP;     // 8192
constexpr int KH    = KD / 2;        // 4096 per k-half block

__device__ __forceinline__ ushort f2bf(float f) {
  return ((__hip_bfloat16_raw)__float2bfloat16(f)).x;
}

// async global->LDS, 16 B per lane. LDS dst MUST be wave-uniform base + lane*16.
__device__ __forceinline__ void gload_lds16(const void* g, void* l) {
  __builtin_amdgcn_global_load_lds(
      (const __attribute__((address_space(1))) unsigned int*)g,
      (__attribute__((address_space(3))) unsigned int*)l, 16, 0, 0);
}

// ---------- 1. rowstats + A-build + zero(out row) + bias zeroing --------------
__global__ __launch_bounds__(256) void build_a_kernel(const float* __restrict__ x,
                                                      ushort* __restrict__ A2,
                                                      float* __restrict__ bias,
                                                      float* __restrict__ out) {
  __shared__ float red[8];
  const int b = blockIdx.x, t = threadIdx.x, lane = t & 63, wv = t >> 6;
  if (b < 4) bias[b * 256 + t] = 0.0f;                     // zero before build_b
  ((float4*)(out + (size_t)b * ODIM))[t] = (float4){0.f, 0.f, 0.f, 0.f};
  const float* xr = x + (size_t)b * IDIM;
  const float4 v = ((const float4*)xr)[t];                 // i = 4t..4t+3
  float mn = fminf(fminf(v.x, v.y), fminf(v.z, v.w));
  float mx = fmaxf(fmaxf(v.x, v.y), fmaxf(v.z, v.w));
#pragma unroll
  for (int off = 32; off >= 1; off >>= 1) {
    mn = fminf(mn, __shfl_xor(mn, off));
    mx = fmaxf(mx, __shfl_xor(mx, off));
  }
  if (lane == 0) { red[wv] = mn; red[4 + wv] = mx; }
  __syncthreads();
  mn = fminf(fminf(red[0], red[1]), fminf(red[2], red[3]));
  mx = fmaxf(fmaxf(red[4], red[5]), fmaxf(red[6], red[7]));
  const float sc = 2.0f / (mx - mn);
  const float of = -mn * sc - 1.0f;

  uint4* adst = (uint4*)(A2 + (size_t)b * KD);
#pragma unroll
  for (int c = 0; c < 4; ++c) {
    const int i = c * 256 + t;                             // lanes consecutive
    const float xn = fmaf(sc, xr[i], of);                  // L1-hot re-read
    const float T2 = 2.f * xn * xn - 1.f;
    const float T3 = 2.f * xn * T2 - xn;
    const float T4 = 2.f * xn * T3 - T2;
    const float T5 = 2.f * xn * T4 - T3;
    const float T6 = 2.f * xn * T5 - T4;
    const float T7 = 2.f * xn * T6 - T5;
    const float T8 = 2.f * xn * T7 - T6;
    uint4 w;
    w.x = (uint)f2bf(xn) | ((uint)f2bf(T2) << 16);         // d' 0,1 = T1,T2
    w.y = (uint)f2bf(T3) | ((uint)f2bf(T4) << 16);
    w.z = (uint)f2bf(T5) | ((uint)f2bf(T6) << 16);
    w.w = (uint)f2bf(T7) | ((uint)f2bf(T8) << 16);
    adst[i] = w;                                           // coalesced 16 B/lane
  }
}

// ---------- 2. B^T[o][i*8+d'] = C[i][o][d'+1] bf16; j==0 -> fp32 bias ----------
__global__ __launch_bounds__(256) void build_b_kernel(const float* __restrict__ coeffs,
                                                      ushort* __restrict__ B2T,
                                                      float* __restrict__ bias) {
  __shared__ __align__(16) ushort tile[64 * 256];          // 32 KB [o_l][i_l*8+d']
  __shared__ float lb[64];
  const int i0 = blockIdx.x * 32;
  const int o0 = blockIdx.y * 64;
  const int t  = threadIdx.x;
  if (t < 64) lb[t] = 0.0f;
  __syncthreads();
  for (int idx = t; idx < 18432; idx += 256) {             // coalesced float reads
    const int i_l = idx / 576;                             // 576 = 64*9
    const int rem = idx - i_l * 576;                       // = o_l*9 + j
    const float v = coeffs[((size_t)(i0 + i_l) * ODIM + o0) * DEG1 + rem];
    const int o_l = rem / 9;
    const int j   = rem - o_l * 9;
    if (j == 0) atomicAdd(&lb[o_l], v);                    // exact fp32 bias path
    else tile[o_l * 256 + i_l * KP + (j - 1)] = f2bf(v);
  }
  __syncthreads();
  for (int idx = t; idx < 2048; idx += 256) {              // coalesced uint4 writes
    const int o_l = idx >> 5;
    const int w   = idx & 31;
    uint4* gdst = (uint4*)(B2T + (size_t)(o0 + o_l) * KD + i0 * KP);
    gdst[w] = ((const uint4*)tile)[idx];
  }
  if (t < 64) atomicAdd(&bias[o0 + t], lb[t]);             // device-scope fp32 add
}

// ---------- 3. GEMM: 256x256 tile, K=4096/block, 8-phase schedule -------------
// K-tile BK=64 = 2 k-halves of 32. LDS: 8 slots x 8192 ushorts; for tile
// parity p: slot p*4+{0,1,2,3} = {A_k0, A_k1, B_k0, B_k1} (each 256 x 32k).
// Per K-tile 4 phases: q0 {rd A m0-3 kh0 + B kh0 | stage A_k1(t+1)};
// q1 {rd A m4-7 kh0, reuse B | stage B_k1(t+1)}; q2 {rd kh1 | stage A_k0(t+2)};
// q3 {rd A m4-7 kh1 | stage B_k0(t+2), vmcnt(4)}. Each stage lands >=4 phases
// before use; boundary vmcnt(4) (8 issued/tile, keep last 2 stages in flight)
// guarantees the next tile's halves. Epilogue: fp32 atomicAdd (+bias if g==0).
#define PHASE(SA, SB, MO, READ_B, STAGE_STMT, TAIL_STMT)                        \
  {                                                                             \
    const ushort* Ap = Sm + (SA) * 8192;                                        \
    _Pragma("unroll")                                                           \
    for (int mi = 0; mi < 4; ++mi)                                              \
      afr[mi] = *(const bf16x8s*)&Ap[abase + ((MO) + mi) * 512];                \
    if (READ_B) {                                                               \
      const ushort* Bp = Sm + (SB) * 8192;                                      \
      _Pragma("unroll")                                                         \
      for (int ni = 0; ni < 4; ++ni)                                            \
        bfr[ni] = *(const bf16x8s*)&Bp[bbase + ni * 512];                       \
    }                                                                           \
    STAGE_STMT;                                                                 \
    __builtin_amdgcn_s_barrier();                                               \
    asm volatile("s_waitcnt lgkmcnt(0)" ::: "memory");                          \
    __builtin_amdgcn_s_setprio(1);                                              \
    _Pragma("unroll")                                                           \
    for (int mi = 0; mi < 4; ++mi)                                              \
      _Pragma("unroll")                                                         \
      for (int ni = 0; ni < 4; ++ni)                                            \
        acc[(MO) + mi][ni] = __builtin_amdgcn_mfma_f32_16x16x32_bf16(           \
            afr[mi], bfr[ni], acc[(MO) + mi][ni], 0, 0, 0);                     \
    __builtin_amdgcn_s_setprio(0);                                              \
    TAIL_STMT;                                                                  \
    __builtin_amdgcn_s_barrier();                                               \
  }

#define TILE(T, P)                                                              \
  {                                                                             \
    const int ko = (T) * 64;                                                    \
    PHASE((P)*4 + 0, (P)*4 + 2, 0, true,                                        \
          if ((T) + 1 < KT) { stage(((P)^1)*4 + 1, aBs, ko + 96); }, ;)         \
    PHASE((P)*4 + 0, (P)*4 + 2, 4, false,                                       \
          if ((T) + 1 < KT) { stage(((P)^1)*4 + 3, bBs, ko + 96); }, ;)         \
    PHASE((P)*4 + 1, (P)*4 + 3, 0, true,                                        \
          if ((T) + 2 < KT) { stage((P)*4 + 0, aBs, ko + 128); }, ;)            \
    PHASE((P)*4 + 1, (P)*4 + 3, 4, false,                                       \
          if ((T) + 2 < KT) { stage((P)*4 + 2, bBs, ko + 128); },               \
          if ((T) < KT - 2) { asm volatile("s_waitcnt vmcnt(4)" ::: "memory"); }\
          else              { asm volatile("s_waitcnt vmcnt(0)" ::: "memory"); })\
  }

__global__ __launch_bounds__(512, 2) void gemm_kernel(const ushort* __restrict__ A2,
                                                      const ushort* __restrict__ B2T,
                                                      const float* __restrict__ bias,
                                                      float* __restrict__ out) {
  constexpr int KT = KH / 64;          // 64 K-tiles per block
  __shared__ __align__(16) ushort Sm[8 * 8192];    // 128 KB -> 1 block/CU

  const int t    = threadIdx.x;
  const int lane = t & 63;
  const int wave = t >> 6;
  const int wr   = wave >> 2;          // 0..1 : 128-row half of the 256-row tile
  const int wc   = wave & 3;           // 0..3 : 64-col quarter of 256 cols
  const int c16  = lane & 15;
  const int quad = lane >> 4;

  // bijective XCD chunk swizzle: XCD k -> row-panels 4k..4k+3, all cols+khalves
  const int orig = blockIdx.y * 4 + blockIdx.x;    // grid (4, 64) -> 0..255
  const int swz  = (orig & 7) * 32 + (orig >> 3);
  const int rowBase = (swz >> 3) * 256;            // 32 row panels
  const int rem     = swz & 7;
  const int colBase = (rem & 3) * 256;             // 4 col blocks
  const int g       = rem >> 2;                    // k-half 0/1

  // staging: thread t covers row t>>2 (+128/sweep), 16B chunk (t&3)^((t>>3)&3)
  // (R13 XOR pair, measured 0 conflicts). Half = 256 rows x 32k = 16 KB = 2 sweeps.
  const int trow = t >> 2;                         // 0..127
  const int scol = (t & 3) ^ ((t >> 3) & 3);
  const ushort* aBs = A2  + (size_t)(rowBase + trow) * KD + (size_t)g * KH + scol * 8;
  const ushort* bBs = B2T + (size_t)(colBase + trow) * KD + (size_t)g * KH + scol * 8;

  auto stage = [&](int slot, const ushort* base, int koff) {   // koff in ushorts
    gload_lds16(base + koff,                 Sm + slot * 8192 + t * 8);
    gload_lds16(base + (size_t)128 * KD + koff, Sm + slot * 8192 + 4096 + t * 8);
  };

  // frag read offsets (ushort idx) inside a 256x32k half-slot (row stride 32)
  const int cx    = (quad ^ ((c16 >> 1) & 3)) * 8;
  const int abase = (wr * 128 + c16) * 32 + cx;    // + mt*512 per 16-row m-tile
  const int bbase = (wc * 64 + c16) * 32 + cx;     // + nt*512 per 16-col n-tile

  f32x4 acc[8][4];
#pragma unroll
  for (int m = 0; m < 8; ++m)
#pragma unroll
    for (int n = 0; n < 4; ++n) acc[m][n] = (f32x4){0.f, 0.f, 0.f, 0.f};

  // prologue: tile0's 4 halves + tile1's kh0 halves (12 loads); oldest 8 done
  stage(0, aBs, 0);   stage(2, bBs, 0);            // A_k0(0), B_k0(0)
  stage(1, aBs, 32);  stage(3, bBs, 32);           // A_k1(0), B_k1(0)
  stage(4, aBs, 64);  stage(6, bBs, 64);           // A_k0(1), B_k0(1)
  asm volatile("s_waitcnt vmcnt(4)" ::: "memory"); // tile0 fully resident
  __builtin_amdgcn_s_barrier();

  bf16x8s afr[4], bfr[4];
  for (int tb = 0; tb < KT; tb += 2) {
    TILE(tb, 0)
    TILE(tb + 1, 1)
  }

  // ---- epilogue: split-K combine via fp32 atomicAdd (out pre-zeroed) ----
#pragma unroll
  for (int ni = 0; ni < 4; ++ni) {
    const int col = colBase + wc * 64 + ni * 16 + c16;
    const float bv = (g == 0) ? bias[col] : 0.0f;  // bias folded into half 0
#pragma unroll
    for (int mi = 0; mi < 8; ++mi) {
      const int r0 = rowBase + wr * 128 + mi * 16 + quad * 4;
#pragma unroll
      for (int r = 0; r < 4; ++r)
        atomicAdd(&out[(size_t)(r0 + r) * ODIM + col], acc[mi][ni][r] + bv);
    }
  }
}

extern "C" void kernel_launch(void* const* d_in, const int* in_sizes, int n_in,
                              void* d_out, int out_size, void* d_ws, size_t ws_size,
                              hipStream_t stream) {
  const float* x      = (const float*)d_in[0];   // [8192,1024] fp32
  const float* coeffs = (const float*)d_in[1];   // [1024,1024,9] fp32
  float* out = (float*)d_out;                    // [8192,1024] fp32

  char* ws = (char*)d_ws;
  float*  bias = (float*)ws;                                        // 4 KB (pad 64K)
  ushort* B2T  = (ushort*)(ws + 65536);                             // 16.78 MB
  ushort* A2   = (ushort*)(ws + 65536 + (size_t)ODIM * KD * 2);     // 134.2 MB
  // total ws: ~151 MB

  build_a_kernel<<<BROWS, 256, 0, stream>>>(x, A2, bias, out);      // + zeroes out
  build_b_kernel<<<dim3(IDIM / 32, ODIM / 64), 256, 0, stream>>>(coeffs, B2T, bias);
  // 256x256 tile, split-K x2: grid (4, 64) = 256 blocks = 1/CU
  gemm_kernel<<<dim3(4, 64), 512, 0, stream>>>(A2, B2T, bias, out);
}

// Round 10
// 285.476 us; speedup vs baseline: 1.0930x; 1.0930x over previous
//
#include <hip/hip_runtime.h>
#include <hip/hip_bf16.h>

// ChebyshevKANLayer: y[b,o] = sum_{i,j} T_j(xhat[b,i]) * C[i,o,j]
// T0==1 folded into fp32 bias; GEMM K = 1024*8 = 8192 (degrees 1..8), bf16 MFMA.
// R16: 16 waves/CU. Wave-count series (4w=158, 8w=129..137) says TLP is the
// remaining gemm lever; 16 waves needs split-K: 1024 thr = 2 k-groups x 8
// waves(64x64), tile 256x128, BK=32/group, per-group triple buffer (144KB).
// Barrier count stays 128 (= R9); R13's conflict-free 4-chunk XOR; counted
// vmcnt(3)/group; setprio; XCD chunk swizzle. launch_bounds(1024,4) caps
// VGPR<=128 so all 16 waves are resident. Split-K epilogue via LDS fp32 with
// stride-132 pad (<=2-way conflicts = free; fixes R14's 524K). zero_bias
// launch folded into build_a (proven R11/R13/R14).
// ws: bias 4KB(pad 64K) | B^T 16.8MB | A 134MB.

typedef __attribute__((ext_vector_type(8))) short bf16x8s;   // MFMA A/B frag (4 VGPRs)
typedef __attribute__((ext_vector_type(4))) float f32x4;     // MFMA C/D frag

constexpr int BROWS = 8192;
constexpr int IDIM  = 1024;
constexpr int ODIM  = 1024;
constexpr int DEG1  = 9;
constexpr int KP    = 8;             // stored degrees 1..8 per input i
constexpr int KD    = IDIM * KP;     // 8192
constexpr int KH    = KD / 2;        // 4096 per k-group

__device__ __forceinline__ ushort f2bf(float f) {
  return ((__hip_bfloat16_raw)__float2bfloat16(f)).x;
}

// async global->LDS, 16 B per lane. LDS dst MUST be wave-uniform base + lane*16.
__device__ __forceinline__ void gload_lds16(const void* g, void* l) {
  __builtin_amdgcn_global_load_lds(
      (const __attribute__((address_space(1))) unsigned int*)g,
      (__attribute__((address_space(3))) unsigned int*)l, 16, 0, 0);
}

// ---------- 1. fused rowstats + A-build (+ bias zeroing in blocks 0..3) -------
__global__ __launch_bounds__(256) void build_a_kernel(const float* __restrict__ x,
                                                      ushort* __restrict__ A2,
                                                      float* __restrict__ bias) {
  __shared__ float red[8];
  const int b = blockIdx.x, t = threadIdx.x, lane = t & 63, wv = t >> 6;
  if (b < 4) bias[b * 256 + t] = 0.0f;                     // zero before build_b
  const float* xr = x + (size_t)b * IDIM;
  const float4 v = ((const float4*)xr)[t];                 // i = 4t..4t+3
  float mn = fminf(fminf(v.x, v.y), fminf(v.z, v.w));
  float mx = fmaxf(fmaxf(v.x, v.y), fmaxf(v.z, v.w));
#pragma unroll
  for (int off = 32; off >= 1; off >>= 1) {
    mn = fminf(mn, __shfl_xor(mn, off));
    mx = fmaxf(mx, __shfl_xor(mx, off));
  }
  if (lane == 0) { red[wv] = mn; red[4 + wv] = mx; }
  __syncthreads();
  mn = fminf(fminf(red[0], red[1]), fminf(red[2], red[3]));
  mx = fmaxf(fmaxf(red[4], red[5]), fmaxf(red[6], red[7]));
  const float sc = 2.0f / (mx - mn);
  const float of = -mn * sc - 1.0f;

  uint4* adst = (uint4*)(A2 + (size_t)b * KD);
#pragma unroll
  for (int c = 0; c < 4; ++c) {
    const int i = c * 256 + t;                             // lanes consecutive
    const float xn = fmaf(sc, xr[i], of);                  // L1-hot re-read
    const float T2 = 2.f * xn * xn - 1.f;
    const float T3 = 2.f * xn * T2 - xn;
    const float T4 = 2.f * xn * T3 - T2;
    const float T5 = 2.f * xn * T4 - T3;
    const float T6 = 2.f * xn * T5 - T4;
    const float T7 = 2.f * xn * T6 - T5;
    const float T8 = 2.f * xn * T7 - T6;
    uint4 w;
    w.x = (uint)f2bf(xn) | ((uint)f2bf(T2) << 16);         // d' 0,1 = T1,T2
    w.y = (uint)f2bf(T3) | ((uint)f2bf(T4) << 16);
    w.z = (uint)f2bf(T5) | ((uint)f2bf(T6) << 16);
    w.w = (uint)f2bf(T7) | ((uint)f2bf(T8) << 16);
    adst[i] = w;                                           // coalesced 16 B/lane
  }
}

// ---------- 2. B^T[o][i*8+d'] = C[i][o][d'+1] bf16; j==0 -> fp32 bias ----------
__global__ __launch_bounds__(256) void build_b_kernel(const float* __restrict__ coeffs,
                                                      ushort* __restrict__ B2T,
                                                      float* __restrict__ bias) {
  __shared__ __align__(16) ushort tile[64 * 256];          // 32 KB [o_l][i_l*8+d']
  __shared__ float lb[64];
  const int i0 = blockIdx.x * 32;
  const int o0 = blockIdx.y * 64;
  const int t  = threadIdx.x;
  if (t < 64) lb[t] = 0.0f;
  __syncthreads();
  for (int idx = t; idx < 18432; idx += 256) {             // coalesced float reads
    const int i_l = idx / 576;                             // 576 = 64*9
    const int rem = idx - i_l * 576;                       // = o_l*9 + j
    const float v = coeffs[((size_t)(i0 + i_l) * ODIM + o0) * DEG1 + rem];
    const int o_l = rem / 9;
    const int j   = rem - o_l * 9;
    if (j == 0) atomicAdd(&lb[o_l], v);                    // exact fp32 bias path
    else tile[o_l * 256 + i_l * KP + (j - 1)] = f2bf(v);
  }
  __syncthreads();
  for (int idx = t; idx < 2048; idx += 256) {              // coalesced uint4 writes
    const int o_l = idx >> 5;
    const int w   = idx & 31;
    uint4* gdst = (uint4*)(B2T + (size_t)(o0 + o_l) * KD + i0 * KP);
    gdst[w] = ((const uint4*)tile)[idx];
  }
  if (t < 64) atomicAdd(&bias[o0 + t], lb[t]);             // device-scope fp32 add
}

// ---------- 3. GEMM: 256x128, 2 k-groups x 8 waves(64x64), BK=32, 16 waves/CU -
// Per K-tile per group: {8 ds_read_b128 | issue 3 gload_lds (2A+1B) | 16 MFMA};
// vmcnt(3) ; s_barrier (block-wide, groups symmetric) -> 128 barriers total.
// Triple buffer per group: reads hit cur; staging hits nb (tile it-1's buffer,
// consumed before the previous barrier). Steady state 6 loads in flight/wave;
// vmcnt(3) completes tile it+1's, leaves it+2's across the barrier.
__global__ __launch_bounds__(1024, 4) void gemm_kernel(const ushort* __restrict__ A2,
                                                       const ushort* __restrict__ B2T,
                                                       const float* __restrict__ bias,
                                                       float* __restrict__ out) {
  constexpr int BK    = 32;
  constexpr int KT    = KH / BK;       // 128 K-tiles per group
  constexpr int ABUFU = 256 * BK;      // 8192 ushorts = 16 KB
  constexpr int BBUFU = 128 * BK;      // 4096 ushorts =  8 KB
  constexpr int BUFSZ = ABUFU + BBUFU; // 12288 ushorts = 24 KB
  constexpr int GSZ   = 3 * BUFSZ;     // 36864 ushorts = 72 KB per group
  __shared__ __align__(16) ushort Sm[2 * GSZ];     // 144 KB -> 1 block/CU

  const int t    = threadIdx.x;
  const int lane = t & 63;
  const int wave = t >> 6;             // 0..15
  const int g    = wave >> 3;          // k-group 0/1
  const int w8   = wave & 7;
  const int wr   = w8 >> 1;            // 0..3 : 64-row M sub-block
  const int wc   = w8 & 1;             // 0..1 : 64-col N sub-block
  const int c16  = lane & 15;
  const int quad = lane >> 4;

  // bijective XCD chunk swizzle (256 wgs % 8 == 0): XCD k -> rows 4k..4k+3, all cols
  const int orig = blockIdx.y * 8 + blockIdx.x;    // grid (8, 32), x = col fastest
  const int swz  = (orig & 7) * 32 + (orig >> 3);
  const int rowBase = (swz >> 3) * 256;
  const int colBase = (swz & 7) * 128;

  // staging (per group, 512 threads): thread tp covers row tp>>2 (+128/sweep),
  // 16B chunk (tp&3)^f(row), f(row)=(row>>1)&3 (R13 scheme, measured 0 conflicts)
  const int tp   = t & 511;
  const int trow = tp >> 2;                        // 0..127
  const int scol = (tp & 3) ^ ((tp >> 3) & 3);     // (tp&3) ^ f(trow)
  const ushort* aB = A2  + (size_t)(rowBase + trow) * KD + (size_t)g * KH + scol * 8;
  const ushort* bB = B2T + (size_t)(colBase + trow) * KD + (size_t)g * KH + scol * 8;
  ushort* SmG = Sm + g * GSZ;                      // group LDS region
  ushort* uA  = SmG + tp * 8;                      // wave-uniform base + lane*16B
  ushort* uB  = SmG + ABUFU + tp * 8;

  auto issA = [&](int buf, int itile, int a) {     // a = 0..1 : 128-row sweeps
    gload_lds16(aB + (size_t)a * (128 * KD) + (size_t)itile * BK,
                uA + buf * BUFSZ + a * 4096);
  };
  auto issB = [&](int buf, int itile) {            // 128 rows in one sweep
    gload_lds16(bB + (size_t)itile * BK, uB + buf * BUFSZ);
  };

  // per-wave LDS read offsets (ushort idx); swizzled 16B chunk = quad ^ f(c16)
  const int cx   = (quad ^ ((c16 >> 1) & 3)) * 8;
  const int aoff = (wr * 64 + c16) * BK + cx;      // + m*16*BK per m-tile
  const int boff = (wc * 64 + c16) * BK + cx;      // + n*16*BK per n-tile

  f32x4 acc[4][4];
#pragma unroll
  for (int m = 0; m < 4; ++m)
#pragma unroll
    for (int n = 0; n < 4; ++n) acc[m][n] = (f32x4){0.f, 0.f, 0.f, 0.f};

  // prologue: stage tiles 0,1 -> bufs 0,1 ; complete tile 0 (3 left in flight)
  issA(0, 0, 0); issA(0, 0, 1); issB(0, 0);
  issA(1, 1, 0); issA(1, 1, 1); issB(1, 1);
  asm volatile("s_waitcnt vmcnt(3)" ::: "memory");
  __builtin_amdgcn_s_barrier();

  int cur = 0;
  for (int it = 0; it < KT; ++it) {
    const ushort* Asb = SmG + cur * BUFSZ;
    const ushort* Bsb = Asb + ABUFU;
    const int nb = (cur >= 1) ? cur - 1 : 2;       // (cur+2)%3: held tile it-1
    const bool pf = (it < KT - 2);

    bf16x8s afr[4], bfr[4];
#pragma unroll
    for (int m = 0; m < 4; ++m)
      afr[m] = *(const bf16x8s*)&Asb[aoff + m * (16 * BK)];
#pragma unroll
    for (int n = 0; n < 4; ++n)
      bfr[n] = *(const bf16x8s*)&Bsb[boff + n * (16 * BK)];

    if (pf) { issA(nb, it + 2, 0); issA(nb, it + 2, 1); issB(nb, it + 2); }

    __builtin_amdgcn_s_setprio(1);
#pragma unroll
    for (int m = 0; m < 4; ++m)
#pragma unroll
      for (int n = 0; n < 4; ++n)
        acc[m][n] = __builtin_amdgcn_mfma_f32_16x16x32_bf16(afr[m], bfr[n],
                                                            acc[m][n], 0, 0, 0);
    __builtin_amdgcn_s_setprio(0);

    if (pf)              { asm volatile("s_waitcnt vmcnt(3)" ::: "memory"); }
    else if (it == KT-2) { asm volatile("s_waitcnt vmcnt(0)" ::: "memory"); }
    __builtin_amdgcn_s_barrier();                  // ONE barrier per K-tile

    cur = (cur == 2) ? 0 : cur + 1;
  }

  // ---- epilogue: combine k-groups via LDS fp32 (stride 132: <=2-way, free) ---
  __syncthreads();                                 // all frag reads done; Sm reusable
  float* Ct = (float*)Sm;                          // 256 x 132 fp32 = 135 KB
  if (g == 1) {
#pragma unroll
    for (int m = 0; m < 4; ++m)
#pragma unroll
      for (int n = 0; n < 4; ++n) {
        const int lr0 = wr * 64 + m * 16 + quad * 4;
        const int cl  = wc * 64 + n * 16 + c16;
#pragma unroll
        for (int r = 0; r < 4; ++r) Ct[(lr0 + r) * 132 + cl] = acc[m][n][r];
      }
  }
  __syncthreads();
  if (g == 0) {
#pragma unroll
    for (int n = 0; n < 4; ++n) {
      const int cl = wc * 64 + n * 16 + c16;
      const float bv = bias[colBase + cl];
#pragma unroll
      for (int m = 0; m < 4; ++m) {
        const int lr0 = wr * 64 + m * 16 + quad * 4;
#pragma unroll
        for (int r = 0; r < 4; ++r)
          out[(size_t)(rowBase + lr0 + r) * ODIM + colBase + cl] =
              acc[m][n][r] + Ct[(lr0 + r) * 132 + cl] + bv;
      }
    }
  }
}

extern "C" void kernel_launch(void* const* d_in, const int* in_sizes, int n_in,
                              void* d_out, int out_size, void* d_ws, size_t ws_size,
                              hipStream_t stream) {
  const float* x      = (const float*)d_in[0];   // [8192,1024] fp32
  const float* coeffs = (const float*)d_in[1];   // [1024,1024,9] fp32
  float* out = (float*)d_out;                    // [8192,1024] fp32

  char* ws = (char*)d_ws;
  float*  bias = (float*)ws;                                        // 4 KB (pad 64K)
  ushort* B2T  = (ushort*)(ws + 65536);                             // 16.78 MB
  ushort* A2   = (ushort*)(ws + 65536 + (size_t)ODIM * KD * 2);     // 134.2 MB
  // total ws: ~151 MB

  build_a_kernel<<<BROWS, 256, 0, stream>>>(x, A2, bias);           // zeroes bias too
  build_b_kernel<<<dim3(IDIM / 32, ODIM / 64), 256, 0, stream>>>(coeffs, B2T, bias);
  // 256x128 tile -> grid (ODIM/128, BROWS/256) = (8, 32) = 256 blocks = 1/CU
  gemm_kernel<<<dim3(ODIM / 128, BROWS / 256), 1024, 0, stream>>>(A2, B2T, bias, out);
}